// Round 4
// baseline (343.028 us; speedup 1.0000x reference)
//
#include <hip/hip_runtime.h>
#include <stdint.h>

typedef unsigned short u16;
typedef __attribute__((ext_vector_type(4))) float f32x4;
typedef __attribute__((ext_vector_type(8))) __bf16 bf16x8;
typedef __attribute__((ext_vector_type(8))) u16 u16x8;
typedef __attribute__((ext_vector_type(4))) u16 u16x4;

__device__ __forceinline__ u16 f2bf(float f) {
  union { float f; uint32_t u; } v; v.f = f;
  uint32_t u = v.u;
  u = u + 0x7FFFu + ((u >> 16) & 1u);
  return (u16)(u >> 16);
}

__device__ __forceinline__ void gload_lds16(const u16* g, u16* l) {
  u16* gg = const_cast<u16*>(g);
  __builtin_amdgcn_global_load_lds(
      (__attribute__((address_space(1))) void*)gg,
      (__attribute__((address_space(3))) void*)l, 16, 0, 0);
}

// ---------------- prep: x (f32) -> bf16 ----------------
__global__ __launch_bounds__(256) void k_cvt_bf16(const float* __restrict__ in,
                                                  u16* __restrict__ out, int n8) {
  int i = blockIdx.x * 256 + threadIdx.x;
  if (i >= n8) return;
  const float4* p = (const float4*)in;
  float4 a = p[(size_t)2 * i];
  float4 b = p[(size_t)2 * i + 1];
  u16x8 r;
  r[0] = f2bf(a.x); r[1] = f2bf(a.y); r[2] = f2bf(a.z); r[3] = f2bf(a.w);
  r[4] = f2bf(b.x); r[5] = f2bf(b.y); r[6] = f2bf(b.z); r[7] = f2bf(b.w);
  *(u16x8*)(out + ((size_t)i << 3)) = r;
}

// ---------------- prep: W' = W + 4 * B @ A, cast to bf16 ----------------
__global__ __launch_bounds__(256) void k_fold_w(const float* __restrict__ W,
                                                const float* __restrict__ Am,
                                                const float* __restrict__ Bm,
                                                u16* __restrict__ out) {
  int t = blockIdx.x * 256 + threadIdx.x;
  int o = t >> 10;
  int i = (t & 1023) << 2;
  const float4 w  = *(const float4*)(W + ((size_t)o << 12) + i);
  const float4 b  = *(const float4*)(Bm + (o << 2));
  const float4 a0 = *(const float4*)(Am + i);
  const float4 a1 = *(const float4*)(Am + 4096 + i);
  const float4 a2 = *(const float4*)(Am + 8192 + i);
  const float4 a3 = *(const float4*)(Am + 12288 + i);
  u16x4 r;
  r[0] = f2bf(w.x + 4.f * (b.x * a0.x + b.y * a1.x + b.z * a2.x + b.w * a3.x));
  r[1] = f2bf(w.y + 4.f * (b.x * a0.y + b.y * a1.y + b.z * a2.y + b.w * a3.y));
  r[2] = f2bf(w.z + 4.f * (b.x * a0.z + b.y * a1.z + b.z * a2.z + b.w * a3.z));
  r[3] = f2bf(w.w + 4.f * (b.x * a0.w + b.y * a1.w + b.z * a2.w + b.w * a3.w));
  *(u16x4*)(out + ((size_t)t << 2)) = r;
}

// ======== ring-4 BK=32 256x256 GEMM with 4 quadrant phases per K-tile ========
// C = A * B^T. 8 waves (2Mx4N), wave-tile 128x64. LDS: 4 ring buffers per
// operand of [256 rows][32 elems] (128 KiB total). Whole-tile guarantee at
// K-tile boundary via counted vmcnt(8) (R2-proven accounting; never 0 in
// loop). Intra-tile: 4 phases, each {quadrant ds_reads | 1 stage unit of
// tile t+3 | barrier | 8 MFMA} — fine interleave without new dependencies.
// Swizzle (R2-proven, 0 conflicts): 16B slot s: dest chunk s&3 holds source
// chunk (s&3)^((s>>3)&3); read chunk = q ^ ((lane>>1)&3).
__global__ __launch_bounds__(512, 2) void k_gemm4f(const u16* __restrict__ Ag,
                                                   const u16* __restrict__ Bg,
                                                   float* __restrict__ C,
                                                   int M, int N, int K) {
  __shared__ __attribute__((aligned(16))) u16 As[4 * 8192];
  __shared__ __attribute__((aligned(16))) u16 Bs[4 * 8192];
  const int tid  = threadIdx.x;
  const int wave = tid >> 6, lane = tid & 63;
  const int wr = wave >> 2, wc = wave & 3;
  const int NT = K >> 5;

  // T1: bijective XCD swizzle (nwg % 8 == 0 guaranteed by launch guard)
  const int gx = gridDim.x;
  const int nwg = gx * gridDim.y;
  const int orig = blockIdx.y * gx + blockIdx.x;
  const int swz = (orig & 7) * (nwg >> 3) + (orig >> 3);
  const int m0 = (swz / gx) * 256;
  const int n0 = (swz % gx) * 256;

  // staging: per operand 1024 slots of 16B; thread owns slots tid, tid+512
  const int srow = tid >> 2;                        // 0..127
  const int csrc = (tid & 3) ^ ((tid >> 3) & 3);
  const u16* pA = Ag + (size_t)(m0 + srow) * K + csrc * 8;
  const u16* pB = Bg + (size_t)(n0 + srow) * K + csrc * 8;
  const size_t K128 = (size_t)128 * K;
  const int l0 = wave << 9;                         // wave-uniform LDS bases
  const int l1 = 4096 + (wave << 9);

#define SU0(nb, kt) gload_lds16(pA + (kt),        As + ((nb) << 13) + l0)
#define SU1(nb, kt) gload_lds16(pA + K128 + (kt), As + ((nb) << 13) + l1)
#define SU2(nb, kt) gload_lds16(pB + (kt),        Bs + ((nb) << 13) + l0)
#define SU3(nb, kt) gload_lds16(pB + K128 + (kt), Bs + ((nb) << 13) + l1)

  // fragment reads: row*32 elems + swizzled chunk
  const int l4 = lane & 15, q = lane >> 4;
  const int ke = ((q ^ ((lane >> 1) & 3)) << 3);
  const int arow = (wr << 7) + l4;                  // + mh*64 + f*16
  const int brow = (wc << 6) + l4;                  // + nh*32 + g*16

  f32x4 acc[8][4] = {};
  bf16x8 ar[4];      // current A-half fragments [f]
  bf16x8 bq[4];      // all B fragments [nh*2+g], persistent across phases

#define LDA_H(buf, mh)                                                         \
  do {                                                                         \
    _Pragma("unroll") for (int f = 0; f < 4; ++f)                              \
      ar[f] = *(const bf16x8*)(As + ((buf) << 13) +                            \
                               ((arow + (mh) * 64 + f * 16) << 5) + ke);       \
  } while (0)
#define LDB_H(buf, nh)                                                         \
  do {                                                                         \
    _Pragma("unroll") for (int g = 0; g < 2; ++g)                              \
      bq[(nh) * 2 + g] = *(const bf16x8*)(Bs + ((buf) << 13) +                 \
                               ((brow + (nh) * 32 + g * 16) << 5) + ke);       \
  } while (0)
#define MFMA8(mh, nh)                                                          \
  do {                                                                         \
    __builtin_amdgcn_s_setprio(1);                                             \
    _Pragma("unroll") for (int f = 0; f < 4; ++f)                              \
      _Pragma("unroll") for (int g = 0; g < 2; ++g)                            \
        acc[(mh) * 4 + f][(nh) * 2 + g] =                                      \
            __builtin_amdgcn_mfma_f32_16x16x32_bf16(                           \
                ar[f], bq[(nh) * 2 + g], acc[(mh) * 4 + f][(nh) * 2 + g],      \
                0, 0, 0);                                                      \
    __builtin_amdgcn_s_setprio(0);                                             \
  } while (0)
#define BAR()                                                                  \
  do {                                                                         \
    __builtin_amdgcn_s_barrier();                                              \
    __builtin_amdgcn_sched_barrier(0);                                         \
  } while (0)

  // prologue: stage tiles 0..2 (12 loads), wait for tile 0 (8 remain in flight)
  for (int t = 0; t < 3; ++t) {
    const int kt = t << 5;
    SU0(t, kt); SU1(t, kt); SU2(t, kt); SU3(t, kt);
  }
  asm volatile("s_waitcnt vmcnt(8)" ::: "memory");
  __builtin_amdgcn_s_barrier();

  for (int t = 0; t < NT; ++t) {
    const int buf = t & 3, nb = (t + 3) & 3;
    const int kt3 = (t + 3) << 5;
    const bool st = (t + 3) < NT;

    // p0: quadrant (0,0) — reads af(mh0) + bq(nh0); stage A-lo of t+3
    LDA_H(buf, 0);
    LDB_H(buf, 0);
    if (st) SU0(nb, kt3);
    BAR();
    MFMA8(0, 0);
    BAR();

    // p1: quadrant (0,1) — reads bq(nh1); stage A-hi of t+3
    LDB_H(buf, 1);
    if (st) SU1(nb, kt3);
    BAR();
    MFMA8(0, 1);
    BAR();

    // p2: quadrant (1,1) — reads af(mh1); stage B-lo of t+3
    LDA_H(buf, 1);
    if (st) SU2(nb, kt3);
    BAR();
    MFMA8(1, 1);
    BAR();

    // p3: quadrant (1,0) — no reads; stage B-hi of t+3; boundary wait
    if (st) SU3(nb, kt3);
    BAR();
    MFMA8(1, 0);
    if (t + 4 <= NT)      { asm volatile("s_waitcnt vmcnt(8)" ::: "memory"); }
    else if (t + 3 <= NT) { asm volatile("s_waitcnt vmcnt(4)" ::: "memory"); }
    else if (t + 2 <= NT) { asm volatile("s_waitcnt vmcnt(0)" ::: "memory"); }
    BAR();
  }

  // epilogue: C/D layout col = lane&15, row = (lane>>4)*4 + reg
  const int crow = m0 + (wr << 7) + (q << 2);
  const int ccol = n0 + (wc << 6) + l4;
#pragma unroll
  for (int i = 0; i < 8; ++i)
#pragma unroll
    for (int j = 0; j < 4; ++j)
#pragma unroll
      for (int v = 0; v < 4; ++v)
        C[(size_t)(crow + i * 16 + v) * N + ccol + j * 16] = acc[i][j][v];
#undef SU0
#undef SU1
#undef SU2
#undef SU3
#undef LDA_H
#undef LDB_H
#undef MFMA8
#undef BAR
}

// ---------------- 128x128 m97-structure GEMM (backup path) ----------------
__global__ __launch_bounds__(256) void k_gemm_bf16(const u16* __restrict__ Ag,
                                                   const u16* __restrict__ Bg,
                                                   float* __restrict__ C,
                                                   int M, int N, int K) {
  __shared__ __attribute__((aligned(16))) u16 As[128 * 32];
  __shared__ __attribute__((aligned(16))) u16 Bs[128 * 32];
  const int tid  = threadIdx.x;
  const int wave = tid >> 6;
  const int lane = tid & 63;
  const int wr = wave >> 1;
  const int wc = wave & 1;
  const int m0 = blockIdx.y * 128;
  const int n0 = blockIdx.x * 128;
  const int c0 = (wave << 6) + lane;
  const int c1 = 256 + c0;
  const u16* gA0 = Ag + (size_t)(m0 + (c0 >> 2)) * K + ((c0 & 3) << 3);
  const u16* gA1 = Ag + (size_t)(m0 + (c1 >> 2)) * K + ((c1 & 3) << 3);
  const u16* gB0 = Bg + (size_t)(n0 + (c0 >> 2)) * K + ((c0 & 3) << 3);
  const u16* gB1 = Bg + (size_t)(n0 + (c1 >> 2)) * K + ((c1 & 3) << 3);
  u16* lA0 = As + (wave << 9);
  u16* lA1 = As + 2048 + (wave << 9);
  u16* lB0 = Bs + (wave << 9);
  u16* lB1 = Bs + 2048 + (wave << 9);
  f32x4 acc[4][4] = {};
  const int aoff = (((wr << 6) + (lane & 15)) << 5) + ((lane >> 4) << 3);
  const int boff = (((wc << 6) + (lane & 15)) << 5) + ((lane >> 4) << 3);
  for (int kt = 0; kt < K; kt += 32) {
    __syncthreads();
    gload_lds16(gA0 + kt, lA0);
    gload_lds16(gA1 + kt, lA1);
    gload_lds16(gB0 + kt, lB0);
    gload_lds16(gB1 + kt, lB1);
    __syncthreads();
    bf16x8 a[4], b[4];
#pragma unroll
    for (int f = 0; f < 4; ++f) {
      a[f] = *(const bf16x8*)(As + aoff + (f << 9));
      b[f] = *(const bf16x8*)(Bs + boff + (f << 9));
    }
#pragma unroll
    for (int i = 0; i < 4; ++i)
#pragma unroll
      for (int j = 0; j < 4; ++j)
        acc[i][j] = __builtin_amdgcn_mfma_f32_16x16x32_bf16(a[i], b[j], acc[i][j], 0, 0, 0);
  }
  const int crow = m0 + (wr << 6) + ((lane >> 4) << 2);
  const int ccol = n0 + (wc << 6) + (lane & 15);
#pragma unroll
  for (int i = 0; i < 4; ++i)
#pragma unroll
    for (int j = 0; j < 4; ++j)
#pragma unroll
      for (int v = 0; v < 4; ++v)
        C[(size_t)(crow + (i << 4) + v) * N + ccol + (j << 4)] = acc[i][j][v];
}

// ---------------- fallback (no workspace): fp32 tiled GEMM ----------------
__global__ __launch_bounds__(256) void k_fallback(const float* __restrict__ X,
                                                  const float* __restrict__ W,
                                                  const float* __restrict__ Am,
                                                  const float* __restrict__ Bm,
                                                  float* __restrict__ C,
                                                  int M, int N, int K) {
  __shared__ float Xs[64][16];
  __shared__ float Ws[64][17];
  const int tid = threadIdx.x;
  const int tn = tid & 15, tm = tid >> 4;
  const int m0 = blockIdx.y * 64, n0 = blockIdx.x * 64;
  float acc[4][4] = {};
  for (int kt = 0; kt < K; kt += 16) {
    __syncthreads();
#pragma unroll
    for (int qq = 0; qq < 4; ++qq) {
      int idx = qq * 256 + tid;
      int r = idx >> 4, c = idx & 15;
      Xs[r][c] = X[(size_t)(m0 + r) * K + kt + c];
      float w = W[(size_t)(n0 + r) * K + kt + c];
      float4 b = *(const float4*)(Bm + ((n0 + r) << 2));
      w += 4.f * (b.x * Am[kt + c] + b.y * Am[4096 + kt + c] +
                  b.z * Am[8192 + kt + c] + b.w * Am[12288 + kt + c]);
      Ws[r][c] = w;
    }
    __syncthreads();
#pragma unroll
    for (int k = 0; k < 16; ++k) {
      float xv[4], wv[4];
#pragma unroll
      for (int i = 0; i < 4; ++i) xv[i] = Xs[tm * 4 + i][k];
#pragma unroll
      for (int j = 0; j < 4; ++j) wv[j] = Ws[tn * 4 + j][k];
#pragma unroll
      for (int i = 0; i < 4; ++i)
#pragma unroll
        for (int j = 0; j < 4; ++j) acc[i][j] += xv[i] * wv[j];
    }
  }
#pragma unroll
  for (int i = 0; i < 4; ++i)
#pragma unroll
    for (int j = 0; j < 4; ++j)
      C[(size_t)(m0 + tm * 4 + i) * N + n0 + tn * 4 + j] = acc[i][j];
}

extern "C" void kernel_launch(void* const* d_in, const int* in_sizes, int n_in,
                              void* d_out, int out_size, void* d_ws, size_t ws_size,
                              hipStream_t stream) {
  const float* x  = (const float*)d_in[0];
  const float* W  = (const float*)d_in[1];
  const float* lA = (const float*)d_in[2];
  const float* lB = (const float*)d_in[3];
  float* out = (float*)d_out;
  const int K = 4096, N = 4096;
  const int M = in_sizes[0] / K;   // 8192
  const size_t need = ((size_t)M + (size_t)N) * (size_t)K * sizeof(u16);

  if (ws_size >= need && (M % 128) == 0) {
    u16* xb = (u16*)d_ws;
    u16* wb = xb + (size_t)M * K;
    const int n8 = M * (K / 8);
    k_cvt_bf16<<<dim3((n8 + 255) / 256), dim3(256), 0, stream>>>(x, xb, n8);
    const int tw = N * (K / 4);
    k_fold_w<<<dim3(tw / 256), dim3(256), 0, stream>>>(W, lA, lB, wb);
    const int nwg = (N / 256) * (M / 256);
    if ((M % 256) == 0 && (N % 256) == 0 && (K % 32) == 0 && K >= 128 && (nwg % 8) == 0) {
      k_gemm4f<<<dim3(N / 256, M / 256), dim3(512), 0, stream>>>(xb, wb, out, M, N, K);
    } else {
      k_gemm_bf16<<<dim3(N / 128, M / 128), dim3(256), 0, stream>>>(xb, wb, out, M, N, K);
    }
  } else {
    k_fallback<<<dim3(N / 64, M / 64), dim3(256), 0, stream>>>(x, W, lA, lB, out, M, N, K);
  }
}

// Round 5
// 329.216 us; speedup vs baseline: 1.0420x; 1.0420x over previous
//
#include <hip/hip_runtime.h>
#include <stdint.h>

typedef unsigned short u16;
typedef __attribute__((ext_vector_type(16))) float f32x16;
typedef __attribute__((ext_vector_type(4))) float f32x4;
typedef __attribute__((ext_vector_type(8))) __bf16 bf16x8;
typedef __attribute__((ext_vector_type(8))) u16 u16x8;
typedef __attribute__((ext_vector_type(4))) u16 u16x4;

__device__ __forceinline__ u16 f2bf(float f) {
  union { float f; uint32_t u; } v; v.f = f;
  uint32_t u = v.u;
  u = u + 0x7FFFu + ((u >> 16) & 1u);
  return (u16)(u >> 16);
}

__device__ __forceinline__ void gload_lds16(const u16* g, u16* l) {
  u16* gg = const_cast<u16*>(g);
  __builtin_amdgcn_global_load_lds(
      (__attribute__((address_space(1))) void*)gg,
      (__attribute__((address_space(3))) void*)l, 16, 0, 0);
}

// ---------------- prep: x (f32) -> bf16 ----------------
__global__ __launch_bounds__(256) void k_cvt_bf16(const float* __restrict__ in,
                                                  u16* __restrict__ out, int n8) {
  int i = blockIdx.x * 256 + threadIdx.x;
  if (i >= n8) return;
  const float4* p = (const float4*)in;
  float4 a = p[(size_t)2 * i];
  float4 b = p[(size_t)2 * i + 1];
  u16x8 r;
  r[0] = f2bf(a.x); r[1] = f2bf(a.y); r[2] = f2bf(a.z); r[3] = f2bf(a.w);
  r[4] = f2bf(b.x); r[5] = f2bf(b.y); r[6] = f2bf(b.z); r[7] = f2bf(b.w);
  *(u16x8*)(out + ((size_t)i << 3)) = r;
}

// ---------------- prep: W' = W + 4 * B @ A, cast to bf16 ----------------
__global__ __launch_bounds__(256) void k_fold_w(const float* __restrict__ W,
                                                const float* __restrict__ Am,
                                                const float* __restrict__ Bm,
                                                u16* __restrict__ out) {
  int t = blockIdx.x * 256 + threadIdx.x;
  int o = t >> 10;
  int i = (t & 1023) << 2;
  const float4 w  = *(const float4*)(W + ((size_t)o << 12) + i);
  const float4 b  = *(const float4*)(Bm + (o << 2));
  const float4 a0 = *(const float4*)(Am + i);
  const float4 a1 = *(const float4*)(Am + 4096 + i);
  const float4 a2 = *(const float4*)(Am + 8192 + i);
  const float4 a3 = *(const float4*)(Am + 12288 + i);
  u16x4 r;
  r[0] = f2bf(w.x + 4.f * (b.x * a0.x + b.y * a1.x + b.z * a2.x + b.w * a3.x));
  r[1] = f2bf(w.y + 4.f * (b.x * a0.y + b.y * a1.y + b.z * a2.y + b.w * a3.y));
  r[2] = f2bf(w.z + 4.f * (b.x * a0.z + b.y * a1.z + b.z * a2.z + b.w * a3.z));
  r[3] = f2bf(w.w + 4.f * (b.x * a0.w + b.y * a1.w + b.z * a2.w + b.w * a3.w));
  *(u16x4*)(out + ((size_t)t << 2)) = r;
}

// ======= R2 skeleton + 32x32x16 MFMA: ring-4 BK=32 256x256, C = A*B^T =======
// 8 waves (2Mx4N), wave-tile 128x64 as 4x2 grid of 32x32 tiles. Staging,
// swizzle, waits IDENTICAL to the proven R2 kernel (vmcnt(8) counted chain,
// 0 bank conflicts). Only the fragment/MFMA/epilogue layer changes:
//   A-frag: row = lane&31, k = (lane>>5)*8 + ks*16
//   C/D   : col = lane&31, row = (reg&3) + 8*(reg>>2) + 4*(lane>>5)  [m74/m101]
__global__ __launch_bounds__(512, 2) void k_gemm32(const u16* __restrict__ Ag,
                                                   const u16* __restrict__ Bg,
                                                   float* __restrict__ C,
                                                   int M, int N, int K) {
  __shared__ __attribute__((aligned(16))) u16 As[4 * 8192];
  __shared__ __attribute__((aligned(16))) u16 Bs[4 * 8192];
  const int tid  = threadIdx.x;
  const int wave = tid >> 6, lane = tid & 63;
  const int wr = wave >> 2, wc = wave & 3;
  const int m0 = blockIdx.y * 256;
  const int n0 = blockIdx.x * 256;
  const int NT = K >> 5;

  // staging: per operand 1024 slots of 16B; thread owns slots tid, tid+512
  // dest chunk-column tid&3 holds source chunk (tid&3)^((row>>1)&3)
  const int srow = tid >> 2;                        // 0..127
  const int csrc = (tid & 3) ^ ((tid >> 3) & 3);
  const u16* pA = Ag + (size_t)(m0 + srow) * K + csrc * 8;
  const u16* pB = Bg + (size_t)(n0 + srow) * K + csrc * 8;
  const size_t K128 = (size_t)128 * K;
  const int l0 = wave << 9;                         // wave-uniform LDS bases
  const int l1 = 4096 + (wave << 9);

#define SU0(nb, kt) gload_lds16(pA + (kt),        As + ((nb) << 13) + l0)
#define SU1(nb, kt) gload_lds16(pA + K128 + (kt), As + ((nb) << 13) + l1)
#define SU2(nb, kt) gload_lds16(pB + (kt),        Bs + ((nb) << 13) + l0)
#define SU3(nb, kt) gload_lds16(pB + K128 + (kt), Bs + ((nb) << 13) + l1)

  // fragment reads: elem offset = row*32 + (chunk ^ ((row>>1)&3))*8
  const int l5 = lane & 31, h = lane >> 5;
  const int sw = (l5 >> 1) & 3;
  const int ce0 = ((h) ^ sw) << 3;                  // ks=0: source chunk h
  const int ce1 = ((2 + h) ^ sw) << 3;              // ks=1: source chunk 2+h
  const int arow = (wr << 7) + l5;                  // + mb*32
  const int brow = (wc << 6) + l5;                  // + nb*32

  f32x16 acc[4][2] = {};   // [mb][nb]
  bf16x8 a2[2][2];         // current mb-pair [i][ks]
  bf16x8 bq[2][2];         // [nb][ks], persistent across the 2 phases

#define LDA32(buf, p)                                                          \
  do {                                                                         \
    _Pragma("unroll") for (int i = 0; i < 2; ++i) {                            \
      const u16* b_ = As + ((buf) << 13) + ((arow + ((p) * 2 + i) * 32) << 5); \
      a2[i][0] = *(const bf16x8*)(b_ + ce0);                                   \
      a2[i][1] = *(const bf16x8*)(b_ + ce1);                                   \
    }                                                                          \
  } while (0)
#define LDB32(buf)                                                             \
  do {                                                                         \
    _Pragma("unroll") for (int nb = 0; nb < 2; ++nb) {                         \
      const u16* b_ = Bs + ((buf) << 13) + ((brow + nb * 32) << 5);            \
      bq[nb][0] = *(const bf16x8*)(b_ + ce0);                                  \
      bq[nb][1] = *(const bf16x8*)(b_ + ce1);                                  \
    }                                                                          \
  } while (0)
#define MFMA8(p)                                                               \
  do {                                                                         \
    __builtin_amdgcn_s_setprio(1);                                             \
    _Pragma("unroll") for (int i = 0; i < 2; ++i)                              \
      _Pragma("unroll") for (int nb = 0; nb < 2; ++nb)                         \
        _Pragma("unroll") for (int ks = 0; ks < 2; ++ks)                       \
          acc[(p) * 2 + i][nb] = __builtin_amdgcn_mfma_f32_32x32x16_bf16(      \
              a2[i][ks], bq[nb][ks], acc[(p) * 2 + i][nb], 0, 0, 0);           \
    __builtin_amdgcn_s_setprio(0);                                             \
  } while (0)

  // prologue: stage tiles 0..2 (12 loads), wait for tile 0 (8 stay in flight)
  for (int t = 0; t < 3; ++t) {
    const int kt = t << 5;
    SU0(t, kt); SU1(t, kt); SU2(t, kt); SU3(t, kt);
  }
  asm volatile("s_waitcnt vmcnt(8)" ::: "memory");
  __builtin_amdgcn_s_barrier();

  for (int t = 0; t < NT; ++t) {
    const int buf = t & 3, nb_ = (t + 3) & 3;
    const int kt3 = (t + 3) << 5;
    const bool st = (t + 3) < NT;

    // ---- p0: mb 0,1 x all nb; reads 4 A + 4 B; stages A(t+3) ----
    LDA32(buf, 0);
    LDB32(buf);
    if (st) { SU0(nb_, kt3); SU1(nb_, kt3); }
    __builtin_amdgcn_s_barrier();
    MFMA8(0);
    __builtin_amdgcn_s_barrier();

    // ---- p1: mb 2,3 x all nb; reads 4 A; stages B(t+3); boundary wait ----
    LDA32(buf, 1);
    if (st) { SU2(nb_, kt3); SU3(nb_, kt3); }
    __builtin_amdgcn_s_barrier();
    MFMA8(1);
    if (t + 4 <= NT)      { asm volatile("s_waitcnt vmcnt(8)" ::: "memory"); }
    else if (t + 3 <= NT) { asm volatile("s_waitcnt vmcnt(4)" ::: "memory"); }
    else if (t + 2 <= NT) { asm volatile("s_waitcnt vmcnt(0)" ::: "memory"); }
    __builtin_amdgcn_s_barrier();
  }

  // epilogue: 32x32 C/D layout (m74/m101): col = lane&31,
  // row = (reg&3) + 8*(reg>>2) + 4*(lane>>5)
  const int crow = m0 + (wr << 7) + (h << 2);
  const int ccol = n0 + (wc << 6) + l5;
#pragma unroll
  for (int mb = 0; mb < 4; ++mb)
#pragma unroll
    for (int nb = 0; nb < 2; ++nb)
#pragma unroll
      for (int r = 0; r < 16; ++r)
        C[(size_t)(crow + mb * 32 + (r & 3) + ((r >> 2) << 3)) * N +
          ccol + nb * 32] = acc[mb][nb][r];
#undef SU0
#undef SU1
#undef SU2
#undef SU3
#undef LDA32
#undef LDB32
#undef MFMA8
}

// ---------------- 128x128 m97-structure GEMM (backup path) ----------------
__global__ __launch_bounds__(256) void k_gemm_bf16(const u16* __restrict__ Ag,
                                                   const u16* __restrict__ Bg,
                                                   float* __restrict__ C,
                                                   int M, int N, int K) {
  __shared__ __attribute__((aligned(16))) u16 As[128 * 32];
  __shared__ __attribute__((aligned(16))) u16 Bs[128 * 32];
  const int tid  = threadIdx.x;
  const int wave = tid >> 6;
  const int lane = tid & 63;
  const int wr = wave >> 1;
  const int wc = wave & 1;
  const int m0 = blockIdx.y * 128;
  const int n0 = blockIdx.x * 128;
  const int c0 = (wave << 6) + lane;
  const int c1 = 256 + c0;
  const u16* gA0 = Ag + (size_t)(m0 + (c0 >> 2)) * K + ((c0 & 3) << 3);
  const u16* gA1 = Ag + (size_t)(m0 + (c1 >> 2)) * K + ((c1 & 3) << 3);
  const u16* gB0 = Bg + (size_t)(n0 + (c0 >> 2)) * K + ((c0 & 3) << 3);
  const u16* gB1 = Bg + (size_t)(n0 + (c1 >> 2)) * K + ((c1 & 3) << 3);
  u16* lA0 = As + (wave << 9);
  u16* lA1 = As + 2048 + (wave << 9);
  u16* lB0 = Bs + (wave << 9);
  u16* lB1 = Bs + 2048 + (wave << 9);
  f32x4 acc[4][4] = {};
  const int aoff = (((wr << 6) + (lane & 15)) << 5) + ((lane >> 4) << 3);
  const int boff = (((wc << 6) + (lane & 15)) << 5) + ((lane >> 4) << 3);
  for (int kt = 0; kt < K; kt += 32) {
    __syncthreads();
    gload_lds16(gA0 + kt, lA0);
    gload_lds16(gA1 + kt, lA1);
    gload_lds16(gB0 + kt, lB0);
    gload_lds16(gB1 + kt, lB1);
    __syncthreads();
    bf16x8 a[4], b[4];
#pragma unroll
    for (int f = 0; f < 4; ++f) {
      a[f] = *(const bf16x8*)(As + aoff + (f << 9));
      b[f] = *(const bf16x8*)(Bs + boff + (f << 9));
    }
#pragma unroll
    for (int i = 0; i < 4; ++i)
#pragma unroll
      for (int j = 0; j < 4; ++j)
        acc[i][j] = __builtin_amdgcn_mfma_f32_16x16x32_bf16(a[i], b[j], acc[i][j], 0, 0, 0);
  }
  const int crow = m0 + (wr << 6) + ((lane >> 4) << 2);
  const int ccol = n0 + (wc << 6) + (lane & 15);
#pragma unroll
  for (int i = 0; i < 4; ++i)
#pragma unroll
    for (int j = 0; j < 4; ++j)
#pragma unroll
      for (int v = 0; v < 4; ++v)
        C[(size_t)(crow + (i << 4) + v) * N + ccol + (j << 4)] = acc[i][j][v];
}

// ---------------- fallback (no workspace): fp32 tiled GEMM ----------------
__global__ __launch_bounds__(256) void k_fallback(const float* __restrict__ X,
                                                  const float* __restrict__ W,
                                                  const float* __restrict__ Am,
                                                  const float* __restrict__ Bm,
                                                  float* __restrict__ C,
                                                  int M, int N, int K) {
  __shared__ float Xs[64][16];
  __shared__ float Ws[64][17];
  const int tid = threadIdx.x;
  const int tn = tid & 15, tm = tid >> 4;
  const int m0 = blockIdx.y * 64, n0 = blockIdx.x * 64;
  float acc[4][4] = {};
  for (int kt = 0; kt < K; kt += 16) {
    __syncthreads();
#pragma unroll
    for (int qq = 0; qq < 4; ++qq) {
      int idx = qq * 256 + tid;
      int r = idx >> 4, c = idx & 15;
      Xs[r][c] = X[(size_t)(m0 + r) * K + kt + c];
      float w = W[(size_t)(n0 + r) * K + kt + c];
      float4 b = *(const float4*)(Bm + ((n0 + r) << 2));
      w += 4.f * (b.x * Am[kt + c] + b.y * Am[4096 + kt + c] +
                  b.z * Am[8192 + kt + c] + b.w * Am[12288 + kt + c]);
      Ws[r][c] = w;
    }
    __syncthreads();
#pragma unroll
    for (int k = 0; k < 16; ++k) {
      float xv[4], wv[4];
#pragma unroll
      for (int i = 0; i < 4; ++i) xv[i] = Xs[tm * 4 + i][k];
#pragma unroll
      for (int j = 0; j < 4; ++j) wv[j] = Ws[tn * 4 + j][k];
#pragma unroll
      for (int i = 0; i < 4; ++i)
#pragma unroll
        for (int j = 0; j < 4; ++j) acc[i][j] += xv[i] * wv[j];
    }
  }
#pragma unroll
  for (int i = 0; i < 4; ++i)
#pragma unroll
    for (int j = 0; j < 4; ++j)
      C[(size_t)(m0 + tm * 4 + i) * N + n0 + tn * 4 + j] = acc[i][j];
}

extern "C" void kernel_launch(void* const* d_in, const int* in_sizes, int n_in,
                              void* d_out, int out_size, void* d_ws, size_t ws_size,
                              hipStream_t stream) {
  const float* x  = (const float*)d_in[0];
  const float* W  = (const float*)d_in[1];
  const float* lA = (const float*)d_in[2];
  const float* lB = (const float*)d_in[3];
  float* out = (float*)d_out;
  const int K = 4096, N = 4096;
  const int M = in_sizes[0] / K;   // 8192
  const size_t need = ((size_t)M + (size_t)N) * (size_t)K * sizeof(u16);

  if (ws_size >= need && (M % 128) == 0) {
    u16* xb = (u16*)d_ws;
    u16* wb = xb + (size_t)M * K;
    const int n8 = M * (K / 8);
    k_cvt_bf16<<<dim3((n8 + 255) / 256), dim3(256), 0, stream>>>(x, xb, n8);
    const int tw = N * (K / 4);
    k_fold_w<<<dim3(tw / 256), dim3(256), 0, stream>>>(W, lA, lB, wb);
    if ((M % 256) == 0 && (N % 256) == 0 && (K % 32) == 0 && K >= 128) {
      k_gemm32<<<dim3(N / 256, M / 256), dim3(512), 0, stream>>>(xb, wb, out, M, N, K);
    } else {
      k_gemm_bf16<<<dim3(N / 128, M / 128), dim3(256), 0, stream>>>(xb, wb, out, M, N, K);
    }
  } else {
    k_fallback<<<dim3(N / 64, M / 64), dim3(256), 0, stream>>>(x, W, lA, lB, out, M, N, K);
  }
}

// Round 6
// 317.321 us; speedup vs baseline: 1.0810x; 1.0375x over previous
//
#include <hip/hip_runtime.h>
#include <stdint.h>

typedef unsigned short u16;
typedef __attribute__((ext_vector_type(4))) float f32x4;
typedef __attribute__((ext_vector_type(8))) __bf16 bf16x8;
typedef __attribute__((ext_vector_type(8))) u16 u16x8;
typedef __attribute__((ext_vector_type(4))) u16 u16x4;

__device__ __forceinline__ u16 f2bf(float f) {
  union { float f; uint32_t u; } v; v.f = f;
  uint32_t u = v.u;
  u = u + 0x7FFFu + ((u >> 16) & 1u);
  return (u16)(u >> 16);
}

__device__ __forceinline__ void gload_lds16(const u16* g, u16* l) {
  u16* gg = const_cast<u16*>(g);
  __builtin_amdgcn_global_load_lds(
      (__attribute__((address_space(1))) void*)gg,
      (__attribute__((address_space(3))) void*)l, 16, 0, 0);
}

// ---------------- prep: x (f32) -> bf16 ----------------
__global__ __launch_bounds__(256) void k_cvt_bf16(const float* __restrict__ in,
                                                  u16* __restrict__ out, int n8) {
  int i = blockIdx.x * 256 + threadIdx.x;
  if (i >= n8) return;
  const float4* p = (const float4*)in;
  float4 a = p[(size_t)2 * i];
  float4 b = p[(size_t)2 * i + 1];
  u16x8 r;
  r[0] = f2bf(a.x); r[1] = f2bf(a.y); r[2] = f2bf(a.z); r[3] = f2bf(a.w);
  r[4] = f2bf(b.x); r[5] = f2bf(b.y); r[6] = f2bf(b.z); r[7] = f2bf(b.w);
  *(u16x8*)(out + ((size_t)i << 3)) = r;
}

// ---------------- prep: W' = W + 4 * B @ A, cast to bf16 ----------------
__global__ __launch_bounds__(256) void k_fold_w(const float* __restrict__ W,
                                                const float* __restrict__ Am,
                                                const float* __restrict__ Bm,
                                                u16* __restrict__ out) {
  int t = blockIdx.x * 256 + threadIdx.x;
  int o = t >> 10;
  int i = (t & 1023) << 2;
  const float4 w  = *(const float4*)(W + ((size_t)o << 12) + i);
  const float4 b  = *(const float4*)(Bm + (o << 2));
  const float4 a0 = *(const float4*)(Am + i);
  const float4 a1 = *(const float4*)(Am + 4096 + i);
  const float4 a2 = *(const float4*)(Am + 8192 + i);
  const float4 a3 = *(const float4*)(Am + 12288 + i);
  u16x4 r;
  r[0] = f2bf(w.x + 4.f * (b.x * a0.x + b.y * a1.x + b.z * a2.x + b.w * a3.x));
  r[1] = f2bf(w.y + 4.f * (b.x * a0.y + b.y * a1.y + b.z * a2.y + b.w * a3.y));
  r[2] = f2bf(w.z + 4.f * (b.x * a0.z + b.y * a1.z + b.z * a2.z + b.w * a3.z));
  r[3] = f2bf(w.w + 4.f * (b.x * a0.w + b.y * a1.w + b.z * a2.w + b.w * a3.w));
  *(u16x4*)(out + ((size_t)t << 2)) = r;
}

// ======== R2 skeleton + staggered-release barriers + T1 XCD swizzle ========
// C = A * B^T. Ring-4 BK=32, 256x256 tile, 8 waves (2Mx4N), wave 128x64.
// Proven R2 pieces: staging swizzle (0 conflicts), counted vmcnt(8) chain
// (never 0 in loop), setprio around 16-MFMA clusters.
// New: after each mid-phase barrier, EXPLICIT s_waitcnt lgkmcnt(0) +
// ONE sched_barrier(0) before the MFMA cluster (rule #18) — waves release
// from the barrier staggered by LDS-queue completion, so early waves' MFMA
// overlaps late waves' ds_read drain (breaks the 44.7% lockstep bound).
__global__ __launch_bounds__(512, 2) void k_gemm8p(const u16* __restrict__ Ag,
                                                   const u16* __restrict__ Bg,
                                                   float* __restrict__ C,
                                                   int M, int N, int K) {
  __shared__ __attribute__((aligned(16))) u16 As[4 * 8192];
  __shared__ __attribute__((aligned(16))) u16 Bs[4 * 8192];
  const int tid  = threadIdx.x;
  const int wave = tid >> 6, lane = tid & 63;
  const int wr = wave >> 2, wc = wave & 3;   // 2 x 4 wave grid
  const int NT = K >> 5;

  // T1: bijective XCD swizzle (chunked); identity if nwg not divisible by 8
  const int gx = gridDim.x;
  const int nwg = gx * gridDim.y;
  const int orig = blockIdx.y * gx + blockIdx.x;
  const int swz = ((nwg & 7) == 0) ? ((orig & 7) * (nwg >> 3) + (orig >> 3)) : orig;
  const int m0 = (swz / gx) * 256;
  const int n0 = (swz % gx) * 256;

  // staging: 1024 chunks/tile/operand; thread owns chunks tid and tid+512.
  // chunk c -> row c>>2, LDS slot c&3; source k-chunk = (c&3) ^ ((c>>3)&3)
  const int srow = tid >> 2;
  const int csrc = (tid & 3) ^ ((tid >> 3) & 3);
  const u16* gA0 = Ag + (size_t)(m0 + srow) * K + csrc * 8;
  const u16* gB0 = Bg + (size_t)(n0 + srow) * K + csrc * 8;
  const size_t K128 = (size_t)128 * K;
  const int l0 = wave << 9;                  // wave-uniform LDS bases (elems)
  const int l1 = 4096 + (wave << 9);

  // fragment reads: row = base + (lane&15), k-chunk swizzled per lane
  const int l4 = lane & 15;
  const int ke = (((lane >> 4) ^ ((lane >> 1) & 3)) << 3);  // elem offset
  const int arow = (wr << 7) + l4;
  const int brow = (wc << 6) + l4;

  f32x4 acc[8][4] = {};

  // prologue: stage tiles 0..2 (12 loads), keep newest 8 in flight
  for (int t = 0; t < 3; ++t) {
    const int kt = t << 5;
    u16* sa = As + (t << 13);
    u16* sb = Bs + (t << 13);
    gload_lds16(gA0 + kt, sa + l0);
    gload_lds16(gA0 + K128 + kt, sa + l1);
    gload_lds16(gB0 + kt, sb + l0);
    gload_lds16(gB0 + K128 + kt, sb + l1);
  }
  asm volatile("s_waitcnt vmcnt(8)" ::: "memory");   // tile 0 landed
  __builtin_amdgcn_s_barrier();

  for (int t = 0; t < NT; ++t) {
    const u16* a_ = As + ((t & 3) << 13);
    const u16* b_ = Bs + ((t & 3) << 13);
    const bool stage = (t + 3) < NT;
    const int kt3 = (t + 3) << 5;
    u16* sa = As + (((t + 3) & 3) << 13);
    u16* sb = Bs + (((t + 3) & 3) << 13);

    // ---- phase 0 (rows wr*128 + [0,64)) : 8 ds_reads + A-stage ----
    bf16x8 af[4], bq[4];
#pragma unroll
    for (int f = 0; f < 4; ++f)
      af[f] = *(const bf16x8*)(a_ + (arow + f * 16) * 32 + ke);
#pragma unroll
    for (int f = 0; f < 4; ++f)
      bq[f] = *(const bf16x8*)(b_ + (brow + f * 16) * 32 + ke);
    if (stage) {
      gload_lds16(gA0 + kt3, sa + l0);
      gload_lds16(gA0 + K128 + kt3, sa + l1);
    }
    __builtin_amdgcn_s_barrier();
    asm volatile("s_waitcnt lgkmcnt(0)" ::: "memory");  // staggered release
    __builtin_amdgcn_sched_barrier(0);                  // pin MFMA after wait
    __builtin_amdgcn_s_setprio(1);
#pragma unroll
    for (int f = 0; f < 4; ++f)
#pragma unroll
      for (int j = 0; j < 4; ++j)
        acc[f][j] = __builtin_amdgcn_mfma_f32_16x16x32_bf16(af[f], bq[j], acc[f][j], 0, 0, 0);
    __builtin_amdgcn_s_setprio(0);
    __builtin_amdgcn_s_barrier();

    // ---- phase 1 (rows wr*128 + [64,128)) : 4 ds_reads + B-stage ----
#pragma unroll
    for (int f = 0; f < 4; ++f)
      af[f] = *(const bf16x8*)(a_ + (arow + 64 + f * 16) * 32 + ke);
    if (stage) {
      gload_lds16(gB0 + kt3, sb + l0);
      gload_lds16(gB0 + K128 + kt3, sb + l1);
    }
    __builtin_amdgcn_s_barrier();
    asm volatile("s_waitcnt lgkmcnt(0)" ::: "memory");
    __builtin_amdgcn_sched_barrier(0);
    __builtin_amdgcn_s_setprio(1);
#pragma unroll
    for (int f = 0; f < 4; ++f)
#pragma unroll
      for (int j = 0; j < 4; ++j)
        acc[4 + f][j] = __builtin_amdgcn_mfma_f32_16x16x32_bf16(af[f], bq[j], acc[4 + f][j], 0, 0, 0);
    __builtin_amdgcn_s_setprio(0);
    // counted wait: guarantee tile t+1 landed before next iteration's reads.
    if (t + 4 <= NT)      { asm volatile("s_waitcnt vmcnt(8)" ::: "memory"); }
    else if (t + 3 <= NT) { asm volatile("s_waitcnt vmcnt(4)" ::: "memory"); }
    else if (t + 2 <= NT) { asm volatile("s_waitcnt vmcnt(0)" ::: "memory"); }
    __builtin_amdgcn_s_barrier();
  }

  // epilogue: C/D layout col = lane&15, row = (lane>>4)*4 + reg
  const int crow = m0 + (wr << 7) + ((lane >> 4) << 2);
  const int ccol = n0 + (wc << 6) + l4;
#pragma unroll
  for (int i = 0; i < 8; ++i)
#pragma unroll
    for (int j = 0; j < 4; ++j)
#pragma unroll
      for (int v = 0; v < 4; ++v)
        C[(size_t)(crow + i * 16 + v) * N + ccol + j * 16] = acc[i][j][v];
}

// ---------------- 128x128 m97-structure GEMM (backup path) ----------------
__global__ __launch_bounds__(256) void k_gemm_bf16(const u16* __restrict__ Ag,
                                                   const u16* __restrict__ Bg,
                                                   float* __restrict__ C,
                                                   int M, int N, int K) {
  __shared__ __attribute__((aligned(16))) u16 As[128 * 32];
  __shared__ __attribute__((aligned(16))) u16 Bs[128 * 32];
  const int tid  = threadIdx.x;
  const int wave = tid >> 6;
  const int lane = tid & 63;
  const int wr = wave >> 1;
  const int wc = wave & 1;
  const int m0 = blockIdx.y * 128;
  const int n0 = blockIdx.x * 128;
  const int c0 = (wave << 6) + lane;
  const int c1 = 256 + c0;
  const u16* gA0 = Ag + (size_t)(m0 + (c0 >> 2)) * K + ((c0 & 3) << 3);
  const u16* gA1 = Ag + (size_t)(m0 + (c1 >> 2)) * K + ((c1 & 3) << 3);
  const u16* gB0 = Bg + (size_t)(n0 + (c0 >> 2)) * K + ((c0 & 3) << 3);
  const u16* gB1 = Bg + (size_t)(n0 + (c1 >> 2)) * K + ((c1 & 3) << 3);
  u16* lA0 = As + (wave << 9);
  u16* lA1 = As + 2048 + (wave << 9);
  u16* lB0 = Bs + (wave << 9);
  u16* lB1 = Bs + 2048 + (wave << 9);
  f32x4 acc[4][4] = {};
  const int aoff = (((wr << 6) + (lane & 15)) << 5) + ((lane >> 4) << 3);
  const int boff = (((wc << 6) + (lane & 15)) << 5) + ((lane >> 4) << 3);
  for (int kt = 0; kt < K; kt += 32) {
    __syncthreads();
    gload_lds16(gA0 + kt, lA0);
    gload_lds16(gA1 + kt, lA1);
    gload_lds16(gB0 + kt, lB0);
    gload_lds16(gB1 + kt, lB1);
    __syncthreads();
    bf16x8 a[4], b[4];
#pragma unroll
    for (int f = 0; f < 4; ++f) {
      a[f] = *(const bf16x8*)(As + aoff + (f << 9));
      b[f] = *(const bf16x8*)(Bs + boff + (f << 9));
    }
#pragma unroll
    for (int i = 0; i < 4; ++i)
#pragma unroll
      for (int j = 0; j < 4; ++j)
        acc[i][j] = __builtin_amdgcn_mfma_f32_16x16x32_bf16(a[i], b[j], acc[i][j], 0, 0, 0);
  }
  const int crow = m0 + (wr << 6) + ((lane >> 4) << 2);
  const int ccol = n0 + (wc << 6) + (lane & 15);
#pragma unroll
  for (int i = 0; i < 4; ++i)
#pragma unroll
    for (int j = 0; j < 4; ++j)
#pragma unroll
      for (int v = 0; v < 4; ++v)
        C[(size_t)(crow + (i << 4) + v) * N + ccol + (j << 4)] = acc[i][j][v];
}

// ---------------- fallback (no workspace): fp32 tiled GEMM ----------------
__global__ __launch_bounds__(256) void k_fallback(const float* __restrict__ X,
                                                  const float* __restrict__ W,
                                                  const float* __restrict__ Am,
                                                  const float* __restrict__ Bm,
                                                  float* __restrict__ C,
                                                  int M, int N, int K) {
  __shared__ float Xs[64][16];
  __shared__ float Ws[64][17];
  const int tid = threadIdx.x;
  const int tn = tid & 15, tm = tid >> 4;
  const int m0 = blockIdx.y * 64, n0 = blockIdx.x * 64;
  float acc[4][4] = {};
  for (int kt = 0; kt < K; kt += 16) {
    __syncthreads();
#pragma unroll
    for (int qq = 0; qq < 4; ++qq) {
      int idx = qq * 256 + tid;
      int r = idx >> 4, c = idx & 15;
      Xs[r][c] = X[(size_t)(m0 + r) * K + kt + c];
      float w = W[(size_t)(n0 + r) * K + kt + c];
      float4 b = *(const float4*)(Bm + ((n0 + r) << 2));
      w += 4.f * (b.x * Am[kt + c] + b.y * Am[4096 + kt + c] +
                  b.z * Am[8192 + kt + c] + b.w * Am[12288 + kt + c]);
      Ws[r][c] = w;
    }
    __syncthreads();
#pragma unroll
    for (int k = 0; k < 16; ++k) {
      float xv[4], wv[4];
#pragma unroll
      for (int i = 0; i < 4; ++i) xv[i] = Xs[tm * 4 + i][k];
#pragma unroll
      for (int j = 0; j < 4; ++j) wv[j] = Ws[tn * 4 + j][k];
#pragma unroll
      for (int i = 0; i < 4; ++i)
#pragma unroll
        for (int j = 0; j < 4; ++j) acc[i][j] += xv[i] * wv[j];
    }
  }
#pragma unroll
  for (int i = 0; i < 4; ++i)
#pragma unroll
    for (int j = 0; j < 4; ++j)
      C[(size_t)(m0 + tm * 4 + i) * N + n0 + tn * 4 + j] = acc[i][j];
}

extern "C" void kernel_launch(void* const* d_in, const int* in_sizes, int n_in,
                              void* d_out, int out_size, void* d_ws, size_t ws_size,
                              hipStream_t stream) {
  const float* x  = (const float*)d_in[0];
  const float* W  = (const float*)d_in[1];
  const float* lA = (const float*)d_in[2];
  const float* lB = (const float*)d_in[3];
  float* out = (float*)d_out;
  const int K = 4096, N = 4096;
  const int M = in_sizes[0] / K;   // 8192
  const size_t need = ((size_t)M + (size_t)N) * (size_t)K * sizeof(u16);

  if (ws_size >= need && (M % 128) == 0) {
    u16* xb = (u16*)d_ws;
    u16* wb = xb + (size_t)M * K;
    const int n8 = M * (K / 8);
    k_cvt_bf16<<<dim3((n8 + 255) / 256), dim3(256), 0, stream>>>(x, xb, n8);
    const int tw = N * (K / 4);
    k_fold_w<<<dim3(tw / 256), dim3(256), 0, stream>>>(W, lA, lB, wb);
    if ((M % 256) == 0 && (N % 256) == 0 && (K % 32) == 0 && K >= 128) {
      k_gemm8p<<<dim3(N / 256, M / 256), dim3(512), 0, stream>>>(xb, wb, out, M, N, K);
    } else {
      k_gemm_bf16<<<dim3(N / 128, M / 128), dim3(256), 0, stream>>>(xb, wb, out, M, N, K);
    }
  } else {
    k_fallback<<<dim3(N / 64, M / 64), dim3(256), 0, stream>>>(x, W, lA, lB, out, M, N, K);
  }
}

// Round 7
// 296.341 us; speedup vs baseline: 1.1575x; 1.0708x over previous
//
#include <hip/hip_runtime.h>
#include <stdint.h>

typedef unsigned short u16;
typedef __attribute__((ext_vector_type(4))) float f32x4;
typedef __attribute__((ext_vector_type(8))) __bf16 bf16x8;
typedef __attribute__((ext_vector_type(8))) u16 u16x8;
typedef __attribute__((ext_vector_type(4))) u16 u16x4;

__device__ __forceinline__ u16 f2bf(float f) {
  union { float f; uint32_t u; } v; v.f = f;
  uint32_t u = v.u;
  u = u + 0x7FFFu + ((u >> 16) & 1u);
  return (u16)(u >> 16);
}

__device__ __forceinline__ void gload_lds16(const u16* g, u16* l) {
  u16* gg = const_cast<u16*>(g);
  __builtin_amdgcn_global_load_lds(
      (__attribute__((address_space(1))) void*)gg,
      (__attribute__((address_space(3))) void*)l, 16, 0, 0);
}

// ---------------- prep: x (f32) -> bf16 ----------------
__global__ __launch_bounds__(256) void k_cvt_bf16(const float* __restrict__ in,
                                                  u16* __restrict__ out, int n8) {
  int i = blockIdx.x * 256 + threadIdx.x;
  if (i >= n8) return;
  const float4* p = (const float4*)in;
  float4 a = p[(size_t)2 * i];
  float4 b = p[(size_t)2 * i + 1];
  u16x8 r;
  r[0] = f2bf(a.x); r[1] = f2bf(a.y); r[2] = f2bf(a.z); r[3] = f2bf(a.w);
  r[4] = f2bf(b.x); r[5] = f2bf(b.y); r[6] = f2bf(b.z); r[7] = f2bf(b.w);
  *(u16x8*)(out + ((size_t)i << 3)) = r;
}

// ---------------- prep: W' = W + 4 * B @ A, cast to bf16 ----------------
__global__ __launch_bounds__(256) void k_fold_w(const float* __restrict__ W,
                                                const float* __restrict__ Am,
                                                const float* __restrict__ Bm,
                                                u16* __restrict__ out) {
  int t = blockIdx.x * 256 + threadIdx.x;
  int o = t >> 10;
  int i = (t & 1023) << 2;
  const float4 w  = *(const float4*)(W + ((size_t)o << 12) + i);
  const float4 b  = *(const float4*)(Bm + (o << 2));
  const float4 a0 = *(const float4*)(Am + i);
  const float4 a1 = *(const float4*)(Am + 4096 + i);
  const float4 a2 = *(const float4*)(Am + 8192 + i);
  const float4 a3 = *(const float4*)(Am + 12288 + i);
  u16x4 r;
  r[0] = f2bf(w.x + 4.f * (b.x * a0.x + b.y * a1.x + b.z * a2.x + b.w * a3.x));
  r[1] = f2bf(w.y + 4.f * (b.x * a0.y + b.y * a1.y + b.z * a2.y + b.w * a3.y));
  r[2] = f2bf(w.z + 4.f * (b.x * a0.z + b.y * a1.z + b.z * a2.z + b.w * a3.z));
  r[3] = f2bf(w.w + 4.f * (b.x * a0.w + b.y * a1.w + b.z * a2.w + b.w * a3.w));
  *(u16x4*)(out + ((size_t)t << 2)) = r;
}

// ======= m201-structure port: BK=64, quadrant phases, half-tile staging =======
// C = A * B^T.  256x256 tile, 8 waves; INTERLEAVED wave mapping so a phase's
// reads touch exactly one staged A-half + one staged B-half:
//   A row = mh*128 + wr*64 + f*16 + (lane&15)     (wr in 0..1)
//   B row = nh*128 + wc*32 + g*16 + (lane&15)     (wc in 0..3)
// Quadrant order (0,0)(0,1)(1,1)(1,0): per-phase reads {12,4,8,0} (frag reuse).
// Staging: one half-tile (2 gloads) per phase, order A0,B0,B1,A1 of tile t+1
// into buf^1 (true double-buffer: never touches the buffer being read).
// Waits (per-wave load accounting, audited):
//   ph1-end vmcnt(4) -> B1(t) landed (read in ph2)
//   ph2-end vmcnt(4) -> A1(t) landed (read in ph3)
//   ph3-end none      (ph4 has no reads)
//   ph4-end vmcnt(4) -> A0,B0(t+1) landed (read in ph1')   [floor 4 in flight]
// Swizzle (conflict-free): store logical chunk c of row r at phys c^(r&7);
// source pre-swizzled (tid&7)^((tid>>3)&7); read phys = (ks*4+q)^(lane&7).
__global__ __launch_bounds__(512, 2) void k_gemmq(const u16* __restrict__ Ag,
                                                  const u16* __restrict__ Bg,
                                                  float* __restrict__ C,
                                                  int M, int N, int K) {
  __shared__ __attribute__((aligned(16))) u16 As[2 * 16384];
  __shared__ __attribute__((aligned(16))) u16 Bs[2 * 16384];
  const int tid  = threadIdx.x;
  const int wave = tid >> 6, lane = tid & 63;
  const int wr = wave >> 2, wc = wave & 3;
  const int m0 = blockIdx.y * 256, n0 = blockIdx.x * 256;
  const int NT = K >> 6;

  // staging: unit = 64 rows x 64 cols = 8KB = 512 lanes x 16B (1 gload).
  // thread -> row tid>>3 within unit, dest chunk tid&7, source chunk swizzled.
  const int srow = tid >> 3;                       // 0..63
  const int csrc = (tid & 7) ^ (srow & 7);
  const u16* pA = Ag + (size_t)(m0 + srow) * K + csrc * 8;
  const u16* pB = Bg + (size_t)(n0 + srow) * K + csrc * 8;
  const size_t KH = (size_t)128 * K;               // half stride (rows)
  const size_t KU = (size_t)64 * K;                // unit stride (rows)
  const int wb = wave << 9;                        // wave-uniform LDS base

#define SA(nb, h, kt)                                                          \
  do {                                                                         \
    gload_lds16(pA + (h) * KH + (kt),      As + (nb) * 16384 + (h) * 8192 + wb);        \
    gload_lds16(pA + (h) * KH + KU + (kt), As + (nb) * 16384 + (h) * 8192 + 4096 + wb); \
  } while (0)
#define SB(nb, h, kt)                                                          \
  do {                                                                         \
    gload_lds16(pB + (h) * KH + (kt),      Bs + (nb) * 16384 + (h) * 8192 + wb);        \
    gload_lds16(pB + (h) * KH + KU + (kt), Bs + (nb) * 16384 + (h) * 8192 + 4096 + wb); \
  } while (0)

  // fragment read offsets
  const int l4 = lane & 15, q = lane >> 4, l7 = lane & 7;
  const int ke0 = ((q ^ l7) << 3);                 // ks=0 phys chunk ((4|q)^l7 = ke0^32)
  const int aoff = ((wr << 6) + l4) << 6;          // (wr*64 + l4)*64
  const int boff = ((wc << 5) + l4) << 6;          // (wc*32 + l4)*64

  f32x4 acc[8][4] = {};
  bf16x8 ar[4][2];      // current A-half [f][ks]
  bf16x8 bq[2][2][2];   // both B-halves [nh][g][ks]

#define LDA(buf, mh)                                                           \
  do {                                                                         \
    const u16* b_ = As + (buf) * 16384 + (mh) * 8192 + aoff;                   \
    _Pragma("unroll") for (int f = 0; f < 4; ++f) {                            \
      ar[f][0] = *(const bf16x8*)(b_ + f * 1024 + ke0);                        \
      ar[f][1] = *(const bf16x8*)(b_ + f * 1024 + (ke0 ^ 32));                 \
    }                                                                          \
  } while (0)
#define LDB(buf, nh)                                                           \
  do {                                                                         \
    const u16* b_ = Bs + (buf) * 16384 + (nh) * 8192 + boff;                   \
    _Pragma("unroll") for (int g = 0; g < 2; ++g) {                            \
      bq[nh][g][0] = *(const bf16x8*)(b_ + g * 1024 + ke0);                    \
      bq[nh][g][1] = *(const bf16x8*)(b_ + g * 1024 + (ke0 ^ 32));             \
    }                                                                          \
  } while (0)
#define MFMA16(mh, nh)                                                         \
  do {                                                                         \
    __builtin_amdgcn_s_setprio(1);                                             \
    _Pragma("unroll") for (int f = 0; f < 4; ++f)                              \
      _Pragma("unroll") for (int g = 0; g < 2; ++g)                            \
        _Pragma("unroll") for (int ks = 0; ks < 2; ++ks)                       \
          acc[(mh) * 4 + f][(nh) * 2 + g] =                                    \
              __builtin_amdgcn_mfma_f32_16x16x32_bf16(                         \
                  ar[f][ks], bq[nh][g][ks], acc[(mh) * 4 + f][(nh) * 2 + g],   \
                  0, 0, 0);                                                    \
    __builtin_amdgcn_s_setprio(0);                                             \
  } while (0)

  // prologue: stage tile 0 in consumption order A0,B0,B1,A1
  SA(0, 0, 0);
  SB(0, 0, 0);
  SB(0, 1, 0);
  SA(0, 1, 0);
  asm volatile("s_waitcnt vmcnt(4)" ::: "memory");   // A0,B0 landed
  __builtin_amdgcn_s_barrier();

  for (int t = 0; t < NT; ++t) {
    const int buf = t & 1, nb = buf ^ 1;
    const int kt1 = (t + 1) << 6;
    const bool st = (t + 1) < NT;

    // ---- ph1: quadrant (0,0); reads A0(8)+B0(4); stages A0(t+1) ----
    LDA(buf, 0);
    LDB(buf, 0);
    if (st) SA(nb, 0, kt1);
    asm volatile("s_waitcnt lgkmcnt(8)" ::: "memory");   // pacing (12 reads)
    __builtin_amdgcn_s_barrier();
    asm volatile("s_waitcnt lgkmcnt(0)" ::: "memory");
    MFMA16(0, 0);
    if (st) { asm volatile("s_waitcnt vmcnt(4)" ::: "memory"); }
    else    { asm volatile("s_waitcnt vmcnt(2)" ::: "memory"); }
    __builtin_amdgcn_s_barrier();

    // ---- ph2: quadrant (0,1); reads B1(4); stages B0(t+1) ----
    LDB(buf, 1);
    if (st) SB(nb, 0, kt1);
    __builtin_amdgcn_s_barrier();
    asm volatile("s_waitcnt lgkmcnt(0)" ::: "memory");
    MFMA16(0, 1);
    if (st) { asm volatile("s_waitcnt vmcnt(4)" ::: "memory"); }
    else    { asm volatile("s_waitcnt vmcnt(0)" ::: "memory"); }
    __builtin_amdgcn_s_barrier();

    // ---- ph3: quadrant (1,1); reads A1(8); stages B1(t+1) ----
    LDA(buf, 1);
    if (st) SB(nb, 1, kt1);
    __builtin_amdgcn_s_barrier();
    asm volatile("s_waitcnt lgkmcnt(0)" ::: "memory");
    MFMA16(1, 1);
    __builtin_amdgcn_s_barrier();                        // no vm wait needed

    // ---- ph4: quadrant (1,0); no reads; stages A1(t+1) ----
    if (st) SA(nb, 1, kt1);
    __builtin_amdgcn_s_barrier();
    MFMA16(1, 0);
    if (st) { asm volatile("s_waitcnt vmcnt(4)" ::: "memory"); }
    __builtin_amdgcn_s_barrier();
  }

  // epilogue: C/D col = lane&15, row = (lane>>4)*4 + reg (m89-verified)
#pragma unroll
  for (int i = 0; i < 8; ++i) {
    const int mh = i >> 2, f = i & 3;
    const int row = m0 + mh * 128 + wr * 64 + f * 16 + q * 4;
#pragma unroll
    for (int j = 0; j < 4; ++j) {
      const int nh = j >> 1, g = j & 1;
      const int col = n0 + nh * 128 + wc * 32 + g * 16 + l4;
#pragma unroll
      for (int v = 0; v < 4; ++v)
        C[(size_t)(row + v) * N + col] = acc[i][j][v];
    }
  }
#undef SA
#undef SB
#undef LDA
#undef LDB
#undef MFMA16
}

// ---------------- 128x128 m97-structure GEMM (backup path) ----------------
__global__ __launch_bounds__(256) void k_gemm_bf16(const u16* __restrict__ Ag,
                                                   const u16* __restrict__ Bg,
                                                   float* __restrict__ C,
                                                   int M, int N, int K) {
  __shared__ __attribute__((aligned(16))) u16 As[128 * 32];
  __shared__ __attribute__((aligned(16))) u16 Bs[128 * 32];
  const int tid  = threadIdx.x;
  const int wave = tid >> 6;
  const int lane = tid & 63;
  const int wr = wave >> 1;
  const int wc = wave & 1;
  const int m0 = blockIdx.y * 128;
  const int n0 = blockIdx.x * 128;
  const int c0 = (wave << 6) + lane;
  const int c1 = 256 + c0;
  const u16* gA0 = Ag + (size_t)(m0 + (c0 >> 2)) * K + ((c0 & 3) << 3);
  const u16* gA1 = Ag + (size_t)(m0 + (c1 >> 2)) * K + ((c1 & 3) << 3);
  const u16* gB0 = Bg + (size_t)(n0 + (c0 >> 2)) * K + ((c0 & 3) << 3);
  const u16* gB1 = Bg + (size_t)(n0 + (c1 >> 2)) * K + ((c1 & 3) << 3);
  u16* lA0 = As + (wave << 9);
  u16* lA1 = As + 2048 + (wave << 9);
  u16* lB0 = Bs + (wave << 9);
  u16* lB1 = Bs + 2048 + (wave << 9);
  f32x4 acc[4][4] = {};
  const int aoff = (((wr << 6) + (lane & 15)) << 5) + ((lane >> 4) << 3);
  const int boff = (((wc << 6) + (lane & 15)) << 5) + ((lane >> 4) << 3);
  for (int kt = 0; kt < K; kt += 32) {
    __syncthreads();
    gload_lds16(gA0 + kt, lA0);
    gload_lds16(gA1 + kt, lA1);
    gload_lds16(gB0 + kt, lB0);
    gload_lds16(gB1 + kt, lB1);
    __syncthreads();
    bf16x8 a[4], b[4];
#pragma unroll
    for (int f = 0; f < 4; ++f) {
      a[f] = *(const bf16x8*)(As + aoff + (f << 9));
      b[f] = *(const bf16x8*)(Bs + boff + (f << 9));
    }
#pragma unroll
    for (int i = 0; i < 4; ++i)
#pragma unroll
      for (int j = 0; j < 4; ++j)
        acc[i][j] = __builtin_amdgcn_mfma_f32_16x16x32_bf16(a[i], b[j], acc[i][j], 0, 0, 0);
  }
  const int crow = m0 + (wr << 6) + ((lane >> 4) << 2);
  const int ccol = n0 + (wc << 6) + (lane & 15);
#pragma unroll
  for (int i = 0; i < 4; ++i)
#pragma unroll
    for (int j = 0; j < 4; ++j)
#pragma unroll
      for (int v = 0; v < 4; ++v)
        C[(size_t)(crow + (i << 4) + v) * N + ccol + (j << 4)] = acc[i][j][v];
}

// ---------------- fallback (no workspace): fp32 tiled GEMM ----------------
__global__ __launch_bounds__(256) void k_fallback(const float* __restrict__ X,
                                                  const float* __restrict__ W,
                                                  const float* __restrict__ Am,
                                                  const float* __restrict__ Bm,
                                                  float* __restrict__ C,
                                                  int M, int N, int K) {
  __shared__ float Xs[64][16];
  __shared__ float Ws[64][17];
  const int tid = threadIdx.x;
  const int tn = tid & 15, tm = tid >> 4;
  const int m0 = blockIdx.y * 64, n0 = blockIdx.x * 64;
  float acc[4][4] = {};
  for (int kt = 0; kt < K; kt += 16) {
    __syncthreads();
#pragma unroll
    for (int qq = 0; qq < 4; ++qq) {
      int idx = qq * 256 + tid;
      int r = idx >> 4, c = idx & 15;
      Xs[r][c] = X[(size_t)(m0 + r) * K + kt + c];
      float w = W[(size_t)(n0 + r) * K + kt + c];
      float4 b = *(const float4*)(Bm + ((n0 + r) << 2));
      w += 4.f * (b.x * Am[kt + c] + b.y * Am[4096 + kt + c] +
                  b.z * Am[8192 + kt + c] + b.w * Am[12288 + kt + c]);
      Ws[r][c] = w;
    }
    __syncthreads();
#pragma unroll
    for (int k = 0; k < 16; ++k) {
      float xv[4], wv[4];
#pragma unroll
      for (int i = 0; i < 4; ++i) xv[i] = Xs[tm * 4 + i][k];
#pragma unroll
      for (int j = 0; j < 4; ++j) wv[j] = Ws[tn * 4 + j][k];
#pragma unroll
      for (int i = 0; i < 4; ++i)
#pragma unroll
        for (int j = 0; j < 4; ++j) acc[i][j] += xv[i] * wv[j];
    }
  }
#pragma unroll
  for (int i = 0; i < 4; ++i)
#pragma unroll
    for (int j = 0; j < 4; ++j)
      C[(size_t)(m0 + tm * 4 + i) * N + n0 + tn * 4 + j] = acc[i][j];
}

extern "C" void kernel_launch(void* const* d_in, const int* in_sizes, int n_in,
                              void* d_out, int out_size, void* d_ws, size_t ws_size,
                              hipStream_t stream) {
  const float* x  = (const float*)d_in[0];
  const float* W  = (const float*)d_in[1];
  const float* lA = (const float*)d_in[2];
  const float* lB = (const float*)d_in[3];
  float* out = (float*)d_out;
  const int K = 4096, N = 4096;
  const int M = in_sizes[0] / K;   // 8192
  const size_t need = ((size_t)M + (size_t)N) * (size_t)K * sizeof(u16);

  if (ws_size >= need && (M % 128) == 0) {
    u16* xb = (u16*)d_ws;
    u16* wb = xb + (size_t)M * K;
    const int n8 = M * (K / 8);
    k_cvt_bf16<<<dim3((n8 + 255) / 256), dim3(256), 0, stream>>>(x, xb, n8);
    const int tw = N * (K / 4);
    k_fold_w<<<dim3(tw / 256), dim3(256), 0, stream>>>(W, lA, lB, wb);
    if ((M % 256) == 0 && (N % 256) == 0 && (K % 64) == 0 && K >= 128) {
      k_gemmq<<<dim3(N / 256, M / 256), dim3(512), 0, stream>>>(xb, wb, out, M, N, K);
    } else {
      k_gemm_bf16<<<dim3(N / 128, M / 128), dim3(256), 0, stream>>>(xb, wb, out, M, N, K);
    }
  } else {
    k_fallback<<<dim3(N / 64, M / 64), dim3(256), 0, stream>>>(x, W, lA, lB, out, M, N, K);
  }
}